// Round 1
// baseline (277.573 us; speedup 1.0000x reference)
//
#include <hip/hip_runtime.h>

// loss = sum((input - target)^2) / (N/4), by orthonormality of the 2x2 Haar
// transform (sum of the 4 band MSEs == overall pixel SSE * 4/N).
// N = 4*32*512*512 = 33554432; divisor = N/4 = 8388608.
//
// Harness floor discovered in R5: ~170 us of dur_us is the harness's own
// d_ws 512MB 0xAA fill (77 us @ 6.9 TB/s) + d_in restore — untouchable.
// Controllable part = stage1 (+ tiny stage2).
//
// R6 change (this file): drop __builtin_nontemporal_load. The harness
// restores the 268 MB of inputs via D2D copy right before launch, so the
// inputs are largely Infinity-Cache-resident when stage1 runs. nt loads
// (evict-first / no-allocate) forfeit those LLC hits; plain loads let the
// 256 MiB LLC serve a large fraction of the read stream above HBM rate.
// Predicted: stage1 FETCH_SIZE down, dur_us 250 -> ~225-235 if the theory
// holds; neutral if the ws fill evicts the inputs first.

typedef float fvec4 __attribute__((ext_vector_type(4)));

#define S1_BLOCK 256
#define S1_ITERS 8                       // float4s per thread per tensor
#define S1_CHUNK (S1_BLOCK * S1_ITERS)   // 2048 float4s per block

__global__ __launch_bounds__(S1_BLOCK) void haar_mse_stage1(
    const fvec4* __restrict__ x,
    const fvec4* __restrict__ t,
    float* __restrict__ ws,
    int n4)
{
    const int tid  = threadIdx.x;
    const int base = blockIdx.x * S1_CHUNK + tid;

    float acc0 = 0.0f, acc1 = 0.0f, acc2 = 0.0f, acc3 = 0.0f;

    if (base + (S1_ITERS - 1) * S1_BLOCK < n4) {
        // fast path (always taken for the bench shape): 16 loads in flight
        fvec4 a[S1_ITERS], b[S1_ITERS];
        #pragma unroll
        for (int k = 0; k < S1_ITERS; ++k)
            a[k] = x[base + k * S1_BLOCK];
        #pragma unroll
        for (int k = 0; k < S1_ITERS; ++k)
            b[k] = t[base + k * S1_BLOCK];

        #pragma unroll
        for (int k = 0; k < S1_ITERS; ++k) {
            fvec4 d = a[k] - b[k];
            acc0 = fmaf(d.x, d.x, acc0);
            acc1 = fmaf(d.y, d.y, acc1);
            acc2 = fmaf(d.z, d.z, acc2);
            acc3 = fmaf(d.w, d.w, acc3);
        }
    } else {
        // tail path (not taken for the bench shape)
        for (int k = 0; k < S1_ITERS; ++k) {
            const int i = base + k * S1_BLOCK;
            if (i < n4) {
                fvec4 a = x[i];
                fvec4 b = t[i];
                fvec4 d = a - b;
                acc0 = fmaf(d.x, d.x, acc0);
                acc1 = fmaf(d.y, d.y, acc1);
                acc2 = fmaf(d.z, d.z, acc2);
                acc3 = fmaf(d.w, d.w, acc3);
            }
        }
    }

    float acc = (acc0 + acc1) + (acc2 + acc3);

    // wave (64-lane) shuffle reduction
    #pragma unroll
    for (int off = 32; off > 0; off >>= 1)
        acc += __shfl_down(acc, off, 64);

    __shared__ float wave_sums[4];
    const int wave = tid >> 6;
    const int lane = tid & 63;
    if (lane == 0) wave_sums[wave] = acc;
    __syncthreads();

    if (tid == 0)
        ws[blockIdx.x] = (wave_sums[0] + wave_sums[1]) + (wave_sums[2] + wave_sums[3]);
}

__global__ __launch_bounds__(256) void haar_mse_stage2(
    const float* __restrict__ ws,
    float* __restrict__ out,
    int nblocks,
    float scale)
{
    float s = 0.0f;
    for (int i = threadIdx.x; i < nblocks; i += 256)
        s += ws[i];

    #pragma unroll
    for (int off = 32; off > 0; off >>= 1)
        s += __shfl_down(s, off, 64);

    __shared__ float wave_sums[4];
    const int wave = threadIdx.x >> 6;
    const int lane = threadIdx.x & 63;
    if (lane == 0) wave_sums[wave] = s;
    __syncthreads();

    if (threadIdx.x == 0)
        out[0] = ((wave_sums[0] + wave_sums[1]) + (wave_sums[2] + wave_sums[3])) * scale;
}

extern "C" void kernel_launch(void* const* d_in, const int* in_sizes, int n_in,
                              void* d_out, int out_size, void* d_ws, size_t ws_size,
                              hipStream_t stream) {
    const float* x = (const float*)d_in[0];
    const float* t = (const float*)d_in[1];
    float* out = (float*)d_out;
    float* ws  = (float*)d_ws;

    const int n  = in_sizes[0];   // 33554432
    const int n4 = n / 4;         // 8388608 float4s
    const int nblocks = (n4 + S1_CHUNK - 1) / S1_CHUNK;   // 4096

    haar_mse_stage1<<<nblocks, S1_BLOCK, 0, stream>>>(
        (const fvec4*)x, (const fvec4*)t, ws, n4);

    const float scale = 1.0f / (float)(n / 4);            // 1/8388608
    haar_mse_stage2<<<1, 256, 0, stream>>>(ws, out, nblocks, scale);
}

// Round 2
// 252.742 us; speedup vs baseline: 1.0982x; 1.0982x over previous
//
#include <hip/hip_runtime.h>

// loss = sum((input - target)^2) / (N/4), by orthonormality of the 2x2 Haar
// transform (sum of the 4 band MSEs == overall pixel SSE * 4/N).
// N = 4*32*512*512 = 33554432; divisor = N/4 = 8388608.
//
// Harness floor: ~170 us = d_ws 512MB fill (77us @6.9TB/s) + d_in restore.
// Controllable part = stage1 (+ tiny stage2).
//
// R7 (this file): stage1 was latency-bound, not BW-bound — rocprof showed
// (a) LLC-resident replay passes still took ~100us (data source irrelevant),
// (b) VGPR_Count=32, i.e. the compiler had collapsed the "16 loads in
// flight" batch into shallow load->use pairs, exposing ~900cy HBM latency
// every ~2 loads (VALUBusy 2.7%). Fix: revert to nontemporal loads (plain
// loads' L1/L2 allocation cost +25us with zero benefit in this regime) and
// pin the load cluster with sched_barrier(0) so all 16 loads are truly
// outstanding before the first use. Loads are issued a/b-interleaved so the
// pairwise consumption drains vmcnt incrementally (vmcnt(14), vmcnt(12), ...).
// Predicted: VGPR >= 72, stage1 100 -> ~50-60us, total ~225-235us.

typedef float fvec4 __attribute__((ext_vector_type(4)));

#define S1_BLOCK 256
#define S1_ITERS 8                       // float4s per thread per tensor
#define S1_CHUNK (S1_BLOCK * S1_ITERS)   // 2048 float4s per block

__global__ __launch_bounds__(S1_BLOCK) void haar_mse_stage1(
    const fvec4* __restrict__ x,
    const fvec4* __restrict__ t,
    float* __restrict__ ws,
    int n4)
{
    const int tid  = threadIdx.x;
    const int base = blockIdx.x * S1_CHUNK + tid;

    float acc0 = 0.0f, acc1 = 0.0f, acc2 = 0.0f, acc3 = 0.0f;

    if (base + (S1_ITERS - 1) * S1_BLOCK < n4) {
        // fast path (always taken for the bench shape):
        // issue all 16 nt loads, THEN compute. sched_barrier(0) forbids the
        // scheduler from sinking any load past it, so all 16 results stay
        // live simultaneously (true 16-deep memory pipeline per thread).
        fvec4 a[S1_ITERS], b[S1_ITERS];
        #pragma unroll
        for (int k = 0; k < S1_ITERS; ++k) {
            a[k] = __builtin_nontemporal_load(&x[base + k * S1_BLOCK]);
            b[k] = __builtin_nontemporal_load(&t[base + k * S1_BLOCK]);
        }
        __builtin_amdgcn_sched_barrier(0);

        #pragma unroll
        for (int k = 0; k < S1_ITERS; ++k) {
            fvec4 d = a[k] - b[k];
            acc0 = fmaf(d.x, d.x, acc0);
            acc1 = fmaf(d.y, d.y, acc1);
            acc2 = fmaf(d.z, d.z, acc2);
            acc3 = fmaf(d.w, d.w, acc3);
        }
    } else {
        // tail path (not taken for the bench shape)
        for (int k = 0; k < S1_ITERS; ++k) {
            const int i = base + k * S1_BLOCK;
            if (i < n4) {
                fvec4 a = x[i];
                fvec4 b = t[i];
                fvec4 d = a - b;
                acc0 = fmaf(d.x, d.x, acc0);
                acc1 = fmaf(d.y, d.y, acc1);
                acc2 = fmaf(d.z, d.z, acc2);
                acc3 = fmaf(d.w, d.w, acc3);
            }
        }
    }

    float acc = (acc0 + acc1) + (acc2 + acc3);

    // wave (64-lane) shuffle reduction
    #pragma unroll
    for (int off = 32; off > 0; off >>= 1)
        acc += __shfl_down(acc, off, 64);

    __shared__ float wave_sums[4];
    const int wave = tid >> 6;
    const int lane = tid & 63;
    if (lane == 0) wave_sums[wave] = acc;
    __syncthreads();

    if (tid == 0)
        ws[blockIdx.x] = (wave_sums[0] + wave_sums[1]) + (wave_sums[2] + wave_sums[3]);
}

__global__ __launch_bounds__(256) void haar_mse_stage2(
    const float* __restrict__ ws,
    float* __restrict__ out,
    int nblocks,
    float scale)
{
    float s = 0.0f;
    for (int i = threadIdx.x; i < nblocks; i += 256)
        s += ws[i];

    #pragma unroll
    for (int off = 32; off > 0; off >>= 1)
        s += __shfl_down(s, off, 64);

    __shared__ float wave_sums[4];
    const int wave = threadIdx.x >> 6;
    const int lane = threadIdx.x & 63;
    if (lane == 0) wave_sums[wave] = s;
    __syncthreads();

    if (threadIdx.x == 0)
        out[0] = ((wave_sums[0] + wave_sums[1]) + (wave_sums[2] + wave_sums[3])) * scale;
}

extern "C" void kernel_launch(void* const* d_in, const int* in_sizes, int n_in,
                              void* d_out, int out_size, void* d_ws, size_t ws_size,
                              hipStream_t stream) {
    const float* x = (const float*)d_in[0];
    const float* t = (const float*)d_in[1];
    float* out = (float*)d_out;
    float* ws  = (float*)d_ws;

    const int n  = in_sizes[0];   // 33554432
    const int n4 = n / 4;         // 8388608 float4s
    const int nblocks = (n4 + S1_CHUNK - 1) / S1_CHUNK;   // 4096

    haar_mse_stage1<<<nblocks, S1_BLOCK, 0, stream>>>(
        (const fvec4*)x, (const fvec4*)t, ws, n4);

    const float scale = 1.0f / (float)(n / 4);            // 1/8388608
    haar_mse_stage2<<<1, 256, 0, stream>>>(ws, out, nblocks, scale);
}

// Round 3
// 247.589 us; speedup vs baseline: 1.1211x; 1.0208x over previous
//
#include <hip/hip_runtime.h>

// loss = sum((input - target)^2) / (N/4), by orthonormality of the 2x2 Haar
// transform (sum of the 4 band MSEs == overall pixel SSE * 4/N).
// N = 4*32*512*512 = 33554432; divisor = N/4 = 8388608.
//
// Harness floor: ~170 us = d_ws 512MB fill (78us @6.9TB/s) + d_in restore
// (~90us). Controllable part = stage1 (+ tiny stage2).
//
// R8 (this file): stage1 was structurally latency-bound: 4096 short-lived
// blocks each did ONE 16-deep load burst, drained it, ran an epilogue and
// died — the memory pipe idled between bursts (stage1 ~75us = 3.6 TB/s,
// while the harness fill hits 6.9 TB/s; round-1 LLC-resident replays proved
// data location is irrelevant). Fix: persistent pipelined streaming —
// 1024 blocks (4/CU, fully resident, zero churn), each thread runs 8
// batches of 4 float4/tensor with a double-buffered prefetch loop, so ~8KB
// per wave stays in flight continuously (16 waves/CU x 8KB >> ~9KB needed
// by Little's law at ~900cy). Full unroll keeps buffer indices static.
// Predicted: VGPR ~80-96, stage1 75 -> 45-55us, total ~220-230us.

typedef float fvec4 __attribute__((ext_vector_type(4)));

#define S1_BLOCK   256
#define S1_DEPTH   4                    // float4s per batch per thread per tensor
#define S1_BATCHES 8                    // batches per thread
#define S1_CHUNK   (S1_BLOCK * S1_DEPTH * S1_BATCHES)   // 8192 float4s per tensor per block

__global__ __launch_bounds__(S1_BLOCK) void haar_mse_stage1(
    const fvec4* __restrict__ x,
    const fvec4* __restrict__ t,
    float* __restrict__ ws,
    int n4)
{
    const int tid  = threadIdx.x;
    const int base = blockIdx.x * S1_CHUNK + tid;

    float acc0 = 0.0f, acc1 = 0.0f, acc2 = 0.0f, acc3 = 0.0f;

    if (blockIdx.x * S1_CHUNK + S1_CHUNK <= n4) {
        // fast path (always taken for the bench shape):
        // double-buffered 2-deep pipeline; batch j+1's 8 nt loads are in
        // flight while batch j is consumed. Full unroll -> static indices.
        fvec4 a[2][S1_DEPTH], b[2][S1_DEPTH];

        // prologue: batch 0 into buffer 0
        #pragma unroll
        for (int k = 0; k < S1_DEPTH; ++k) {
            a[0][k] = __builtin_nontemporal_load(&x[base + k * S1_BLOCK]);
            b[0][k] = __builtin_nontemporal_load(&t[base + k * S1_BLOCK]);
        }

        #pragma unroll
        for (int j = 0; j < S1_BATCHES; ++j) {
            const int cur = j & 1;
            const int nxt = cur ^ 1;
            if (j + 1 < S1_BATCHES) {
                const int nb = base + (j + 1) * (S1_DEPTH * S1_BLOCK);
                #pragma unroll
                for (int k = 0; k < S1_DEPTH; ++k) {
                    a[nxt][k] = __builtin_nontemporal_load(&x[nb + k * S1_BLOCK]);
                    b[nxt][k] = __builtin_nontemporal_load(&t[nb + k * S1_BLOCK]);
                }
            }
            // keep the prefetch cluster above the compute (no sinking/hoisting)
            __builtin_amdgcn_sched_barrier(0);
            #pragma unroll
            for (int k = 0; k < S1_DEPTH; ++k) {
                fvec4 d = a[cur][k] - b[cur][k];
                acc0 = fmaf(d.x, d.x, acc0);
                acc1 = fmaf(d.y, d.y, acc1);
                acc2 = fmaf(d.z, d.z, acc2);
                acc3 = fmaf(d.w, d.w, acc3);
            }
        }
    } else {
        // tail path (not taken for the bench shape)
        for (int j = 0; j < S1_BATCHES; ++j) {
            for (int k = 0; k < S1_DEPTH; ++k) {
                const int i = base + j * (S1_DEPTH * S1_BLOCK) + k * S1_BLOCK;
                if (i < n4) {
                    fvec4 av = x[i];
                    fvec4 bv = t[i];
                    fvec4 d = av - bv;
                    acc0 = fmaf(d.x, d.x, acc0);
                    acc1 = fmaf(d.y, d.y, acc1);
                    acc2 = fmaf(d.z, d.z, acc2);
                    acc3 = fmaf(d.w, d.w, acc3);
                }
            }
        }
    }

    float acc = (acc0 + acc1) + (acc2 + acc3);

    // wave (64-lane) shuffle reduction
    #pragma unroll
    for (int off = 32; off > 0; off >>= 1)
        acc += __shfl_down(acc, off, 64);

    __shared__ float wave_sums[4];
    const int wave = tid >> 6;
    const int lane = tid & 63;
    if (lane == 0) wave_sums[wave] = acc;
    __syncthreads();

    if (tid == 0)
        ws[blockIdx.x] = (wave_sums[0] + wave_sums[1]) + (wave_sums[2] + wave_sums[3]);
}

__global__ __launch_bounds__(256) void haar_mse_stage2(
    const float* __restrict__ ws,
    float* __restrict__ out,
    int nblocks,
    float scale)
{
    float s = 0.0f;
    for (int i = threadIdx.x; i < nblocks; i += 256)
        s += ws[i];

    #pragma unroll
    for (int off = 32; off > 0; off >>= 1)
        s += __shfl_down(s, off, 64);

    __shared__ float wave_sums[4];
    const int wave = threadIdx.x >> 6;
    const int lane = threadIdx.x & 63;
    if (lane == 0) wave_sums[wave] = s;
    __syncthreads();

    if (threadIdx.x == 0)
        out[0] = ((wave_sums[0] + wave_sums[1]) + (wave_sums[2] + wave_sums[3])) * scale;
}

extern "C" void kernel_launch(void* const* d_in, const int* in_sizes, int n_in,
                              void* d_out, int out_size, void* d_ws, size_t ws_size,
                              hipStream_t stream) {
    const float* x = (const float*)d_in[0];
    const float* t = (const float*)d_in[1];
    float* out = (float*)d_out;
    float* ws  = (float*)d_ws;

    const int n  = in_sizes[0];   // 33554432
    const int n4 = n / 4;         // 8388608 float4s
    const int nblocks = (n4 + S1_CHUNK - 1) / S1_CHUNK;   // 1024

    haar_mse_stage1<<<nblocks, S1_BLOCK, 0, stream>>>(
        (const fvec4*)x, (const fvec4*)t, ws, n4);

    const float scale = 1.0f / (float)(n / 4);            // 1/8388608
    haar_mse_stage2<<<1, 256, 0, stream>>>(ws, out, nblocks, scale);
}